// Round 2
// baseline (274.341 us; speedup 1.0000x reference)
//
#include <hip/hip_runtime.h>

#define NB 8
#define N1 2048
#define N2 1152
#define KD 1024
#define BM 256
#define BN 144
#define BNP 145     // padded epilogue stride
#define BUFB 25600  // one staging buffer: 25 chunks x 1 KB (16 A + 9 B)
#define GRID (NB * (N1 / BM) * (N2 / BN))  // 512 = 2 blocks/CU exactly
#define BAR_OFF 26316800  // ws offset of 8-byte barrier state (cnt, gen)

typedef __attribute__((ext_vector_type(4))) float f32x4;
typedef __attribute__((ext_vector_type(2))) long i64x2;

__device__ __forceinline__ unsigned pack4_fp8(f32x4 v) {
  int t = __builtin_amdgcn_cvt_pk_fp8_f32(v.x, v.y, 0, false);
  t = __builtin_amdgcn_cvt_pk_fp8_f32(v.z, v.w, t, true);
  return (unsigned)t;
}

__device__ __forceinline__ void async_copy16(const void* g, void* l) {
  __builtin_amdgcn_global_load_lds(
      (const __attribute__((address_space(1))) unsigned int*)g,
      (__attribute__((address_space(3))) unsigned int*)l, 16, 0, 0);
}

// FUSED convert + dist, single compute dispatch (R11).
// R10 post-mortem: hipLaunchCooperativeKernel cannot be graph-captured ->
// launch silently failed (out == 0 exactly). Same fusion, MANUAL grid
// barrier instead:
//  - co-residency GUARANTEED: __launch_bounds__(256,2) caps VGPR<=256 ->
//    2 blocks/CU schedulable; LDS 2x51200 <= 160K; grid 512 = 2 x 256 CUs.
//    Spin barrier cannot deadlock.
//  - barrier state (8 B in ws) zeroed by hipMemsetAsync EVERY launch
//    (graph-safe, R0-proven) -> immune to ws poison and graph replay.
//  - __threadfence() (agent scope: L2 writeback/inv across XCDs) before
//    arrival / after release; agent-scope atomics on cnt/gen.
//  - last arriver zeroes `out` pre-release -> no d_out memset dispatch;
//    self-resetting across replays.
// Phase 1 (convert): 50 rows/block, 1 row/wave/round, 13 rounds; validated
// per-round structure (LDS permute + __syncthreads + coalesced uint4 out).
// Batch b -> XCD b (bid&7) kept: fp8 writes stay hot in local 4MB L2 for
// phase 2 (R8-verified: dist FETCH 12.9 MB vs 26 MB compulsory).
// Phase 2 (dist): byte-identical to the R9-verified dbuf K-loop + epilogue.
// CRITICAL (unchanged): every loop touching acc[][] FULLY UNROLLED; tripwire
// WRITE_SIZE ~26MB (phase-1 fp8) + no scratch.
__global__ __launch_bounds__(256, 2) void fused_kernel(
    const float* __restrict__ x1, const float* __restrict__ x2,
    unsigned char* __restrict__ x1q, unsigned char* __restrict__ x2q,
    float* __restrict__ sq1, float* __restrict__ sq2,
    float* __restrict__ out, unsigned* __restrict__ bar) {
  __shared__ __align__(16) char smem[2 * BUFB];  // 51200 B >= 37120 epilogue

  const int tid = threadIdx.x;
  const int wave = tid >> 6, lane = tid & 63;
  const int bid = blockIdx.x;
  const int b = bid & 7;  // batch -> XCD (both phases)

  // ---------------- phase 1: fp32 -> fp8 convert (50 rows/block) ----------
  {
    const int base = (bid >> 3) * 50;  // first row within batch, 0..3150
    unsigned char* my = (unsigned char*)smem + wave * 1024;
    const int r = 4 * (lane & 15);
    const int q = (r & 31) >> 3;
    const int h = r >> 5;
    const int pos = (lane >> 4) * 64 + q * 16 + h * 8 + (r & 7);
    for (int t = 0; t < 13; ++t) {
      const int ri = t * 4 + wave;  // row index within block, 0..51
      const int rr = base + ri;     // row within batch (x1 rows then x2 rows)
      const float* src = nullptr;
      unsigned char* dst = nullptr;
      float* sqp = nullptr;
      if (ri < 50) {
        if (rr < N1) {
          const int row = b * N1 + rr;
          src = x1 + (size_t)row * KD;
          dst = x1q + (size_t)row * KD;
          sqp = sq1 + row;
        } else {
          const int row = b * N2 + (rr - N1);
          src = x2 + (size_t)row * KD;
          dst = x2q + (size_t)row * KD;
          sqp = sq2 + row;
        }
      }
      float s = 0.f;
      if (ri < 50) {
        const f32x4* s4 = (const f32x4*)src;
#pragma unroll
        for (int i2 = 0; i2 < 4; ++i2) {
          f32x4 v = __builtin_nontemporal_load(&s4[i2 * 64 + lane]);
          *(unsigned*)(my + i2 * 256 + pos) = pack4_fp8(v);
          s += v.x * v.x + v.y * v.y + v.z * v.z + v.w * v.w;
        }
      }
      __syncthreads();  // LDS write -> cross-lane read (all threads reach)
      if (ri < 50) {
        ((uint4*)dst)[lane] = *(const uint4*)(my + lane * 16);
#pragma unroll
        for (int off = 32; off > 0; off >>= 1) s += __shfl_down(s, off);
        if (lane == 0) *sqp = s;
      }
    }
  }

  // ---------------- manual grid barrier (graph-capture-safe) --------------
  __threadfence();   // release: drain fp8/sq stores, L2 writeback (agent)
  __syncthreads();   // whole block done phase 1
  if (tid == 0) {
    unsigned old = __hip_atomic_fetch_add(&bar[0], 1u, __ATOMIC_ACQ_REL,
                                          __HIP_MEMORY_SCOPE_AGENT);
    if (old == GRID - 1) {
      atomicExch(out, 0.0f);  // zero output BEFORE release; replaces memset
      __threadfence();
      __hip_atomic_store(&bar[1], 1u, __ATOMIC_RELEASE,
                         __HIP_MEMORY_SCOPE_AGENT);
    } else {
      while (__hip_atomic_load(&bar[1], __ATOMIC_ACQUIRE,
                               __HIP_MEMORY_SCOPE_AGENT) == 0u) {
        __builtin_amdgcn_s_sleep(2);
      }
    }
  }
  __syncthreads();   // whole block sees release
  __threadfence();   // acquire: invalidate stale L1/L2 before phase-2 reads

  // ---------------- phase 2: dist (R9-verified body, verbatim) ------------
  const int bm = (bid >> 3) & 7;  // fastest: A streams, B-tile L2-hot
  const int bn = bid >> 6;

  const unsigned char* Ag = x1q + ((size_t)b * N1 + bm * BM) * KD;
  const unsigned char* Bg = x2q + ((size_t)b * N2 + bn * BN) * KD;

  // staging: lane -> (row lr, 16B slot sl), fetch the swizzled global group
  const int lr = lane >> 2, sl = lane & 3;
  const int goff = (sl ^ ((lr >> 1) & 3)) * 16;

  // fragments: lane (fr, quad) reads swizzled slot -> global 16B group `quad`
  const int quad = lane >> 4, fr = lane & 15;
  const int fslot = (fr * 4 + (quad ^ ((fr >> 1) & 3))) * 16;

  f32x4 acc[4][9];
#pragma unroll
  for (int i = 0; i < 4; ++i)
#pragma unroll
    for (int j = 0; j < 9; ++j) {
      f32x4 z = {0.f, 0.f, 0.f, 0.f};
      acc[i][j] = z;
    }

  // stage(k0) into buffer `buf`: 25 chunks (0..15 = A 256 rows, 16..24 = B 144)
  auto stage = [&](int buf, int k0) {
    char* base = smem + buf * BUFB;
    for (int j = wave; j < 25; j += 4) {
      const unsigned char* g;
      if (j < 16)
        g = Ag + (size_t)(j * 16 + lr) * KD + k0 + goff;
      else
        g = Bg + (size_t)((j - 16) * 16 + lr) * KD + k0 + goff;
      async_copy16(g, base + j * 1024 + lane * 16);
    }
  };

  stage(0, 0);  // prologue prefetch
  for (int i = 0; i < 16; ++i) {
    const int cur = i & 1;
    __syncthreads();  // drains cur's loads (issued a full iter ago) + guards nxt reuse
    if (i < 15) stage(cur ^ 1, (i + 1) * 64);
    const char* cb = smem + cur * BUFB;

    i64x2 a[4];
#pragma unroll
    for (int tm = 0; tm < 4; ++tm)
      a[tm] = *(const i64x2*)(cb + (wave * 4 + tm) * 1024 + fslot);
#pragma unroll
    for (int tn = 0; tn < 9; ++tn) {
      i64x2 bf = *(const i64x2*)(cb + 16384 + tn * 1024 + fslot);
#pragma unroll
      for (int tm = 0; tm < 4; ++tm) {
        acc[tm][tn] = __builtin_amdgcn_mfma_f32_16x16x32_fp8_fp8(a[tm].x, bf.x, acc[tm][tn], 0, 0, 0);
        acc[tm][tn] = __builtin_amdgcn_mfma_f32_16x16x32_fp8_fp8(a[tm].y, bf.y, acc[tm][tn], 0, 0, 0);
      }
    }
  }

  // ---- epilogue: d = sq1 + sq2 - 2*cross, min over 9-col groups, sum ----
  float s2[9];
#pragma unroll
  for (int tn = 0; tn < 9; ++tn)
    s2[tn] = sq2[(size_t)b * N2 + bn * BN + tn * 16 + fr];

  float s1v[4][4];
#pragma unroll
  for (int tm = 0; tm < 4; ++tm)
#pragma unroll
    for (int rr = 0; rr < 4; ++rr)
      s1v[tm][rr] = sq1[(size_t)b * N1 + bm * BM + wave * 64 + tm * 16 + quad * 4 + rr];

  float* eps = (float*)smem;
  float local = 0.f;
#pragma unroll  // FULL unroll: acc indices must be compile-time constants
  for (int tm = 0; tm < 4; ++tm) {
    __syncthreads();  // K-loop LDS / previous chunk fully consumed
    // D layout (16x16x32, dtype-independent): col = lane&15 (x2 row),
    // row = quad*4 + reg (x1 row). Chunk row = wave*16 + quad*4 + r.
#pragma unroll
    for (int tn = 0; tn < 9; ++tn)
#pragma unroll
      for (int rr = 0; rr < 4; ++rr)
        eps[(wave * 16 + quad * 4 + rr) * BNP + tn * 16 + fr] =
            s1v[tm][rr] + s2[tn] - 2.0f * acc[tm][tn][rr];
    __syncthreads();
    // 64 rows x 16 groups = 1024 groups, 4 per thread
#pragma unroll
    for (int qq = 0; qq < 4; ++qq) {
      int g = tid + qq * 256;
      int row = g >> 4, grp = g & 15;
      const float* p = eps + row * BNP + grp * 9;
      float mn = p[0];
#pragma unroll
      for (int jj = 1; jj < 9; ++jj) mn = fminf(mn, p[jj]);
      local += mn;
    }
  }

#pragma unroll
  for (int off = 32; off > 0; off >>= 1) local += __shfl_down(local, off);
  __syncthreads();
  if (lane == 0) eps[wave] = local;
  __syncthreads();
  if (tid == 0) {
    float s = eps[0] + eps[1] + eps[2] + eps[3];
    // total group count = 8 * 2048 * 1152 / 9 = 2097152
    atomicAdd(out, s * (1.0f / 2097152.0f));
  }
}

extern "C" void kernel_launch(void* const* d_in, const int* in_sizes, int n_in,
                              void* d_out, int out_size, void* d_ws, size_t ws_size,
                              hipStream_t stream) {
  const float* x1 = (const float*)d_in[0];
  const float* x2 = (const float*)d_in[1];
  char* ws = (char*)d_ws;
  const size_t x1q_bytes = (size_t)NB * N1 * KD;  // 16777216
  const size_t x2q_bytes = (size_t)NB * N2 * KD;  // 9437184
  unsigned char* x1q = (unsigned char*)ws;
  unsigned char* x2q = (unsigned char*)(ws + x1q_bytes);
  float* sq1 = (float*)(ws + x1q_bytes + x2q_bytes);
  float* sq2 = (float*)(ws + x1q_bytes + x2q_bytes + (size_t)NB * N1 * 4);
  unsigned* bar = (unsigned*)(ws + BAR_OFF);

  // zero ONLY the 8-byte barrier state each launch (graph-safe, poison-proof)
  (void)hipMemsetAsync(bar, 0, 2 * sizeof(unsigned), stream);
  fused_kernel<<<GRID, 256, 0, stream>>>(x1, x2, x1q, x2q, sq1, sq2,
                                         (float*)d_out, bar);
}

// Round 3
// 150.679 us; speedup vs baseline: 1.8207x; 1.8207x over previous
//
#include <hip/hip_runtime.h>

#define NB 8
#define N1 2048
#define N2 1152
#define KD 1024
#define BM 256
#define BN 144
#define BNP 145     // padded epilogue stride
#define BUFB 25600  // one staging buffer: 25 chunks x 1 KB (16 A + 9 B)
#define NBUF 3      // R12: triple buffer -> counted vmcnt, no drain in loop

typedef __attribute__((ext_vector_type(4))) float f32x4;
typedef __attribute__((ext_vector_type(2))) long i64x2;

__device__ __forceinline__ unsigned pack4_fp8(f32x4 v) {
  int t = __builtin_amdgcn_cvt_pk_fp8_f32(v.x, v.y, 0, false);
  t = __builtin_amdgcn_cvt_pk_fp8_f32(v.z, v.w, t, true);
  return (unsigned)t;
}

__device__ __forceinline__ void async_copy16(const void* g, void* l) {
  __builtin_amdgcn_global_load_lds(
      (const __attribute__((address_space(1))) unsigned int*)g,
      (__attribute__((address_space(3))) unsigned int*)l, 16, 0, 0);
}

// R12: REVERT to 3-kernel structure (R2 fusion: kernel 185us vs <=82us sum;
// grid-barrier + low-TLP phase1 catastrophically slow; and the ~85us dur
// overhead proved dispatch-count-INDEPENDENT). convert = R0-verbatim + out
// zeroing folded in (memset dispatch dropped).
// One WAVE per row. XCD-aligned: bid&7 = batch, so batch b's rows convert on
// XCD b and the fp8 writes (3.3 MB/batch) stay hot in that XCD's 4 MB L2 for
// dist_kernel (R8-verified: dist FETCH 12.9 MB vs 26 MB compulsory).
__global__ __launch_bounds__(256) void convert_kernel(
    const float* __restrict__ x1, const float* __restrict__ x2,
    unsigned char* __restrict__ x1q, unsigned char* __restrict__ x2q,
    float* __restrict__ sq1, float* __restrict__ sq2,
    float* __restrict__ out) {
  __shared__ __align__(16) unsigned char lds[4096];
  if (blockIdx.x == 0 && threadIdx.x == 0) *out = 0.f;  // replaces memset
  int wave = threadIdx.x >> 6, lane = threadIdx.x & 63;
  int bid = blockIdx.x;
  int b = bid & 7;          // batch -> XCD
  int idx = bid >> 3;       // 0..799 within batch
  const float* src;
  unsigned char* dst;
  float* sqp;
  if (idx < N1 / 4) {
    int row = b * N1 + idx * 4 + wave;
    src = x1 + (size_t)row * KD;
    dst = x1q + (size_t)row * KD;
    sqp = sq1 + row;
  } else {
    int row = b * N2 + (idx - N1 / 4) * 4 + wave;
    src = x2 + (size_t)row * KD;
    dst = x2q + (size_t)row * KD;
    sqp = sq2 + row;
  }
  const f32x4* s4 = (const f32x4*)src;
  int r = 4 * (lane & 15);
  int q = (r & 31) >> 3;
  int h = r >> 5;
  int pos = (lane >> 4) * 64 + q * 16 + h * 8 + (r & 7);
  unsigned char* my = lds + wave * 1024;
  float s = 0.f;
#pragma unroll
  for (int i = 0; i < 4; ++i) {
    f32x4 v = __builtin_nontemporal_load(&s4[i * 64 + lane]);
    *(unsigned*)(my + i * 256 + pos) = pack4_fp8(v);
    s += v.x * v.x + v.y * v.y + v.z * v.z + v.w * v.w;
  }
  __syncthreads();  // cross-lane LDS visibility
  ((uint4*)dst)[lane] = *(const uint4*)(my + lane * 16);
#pragma unroll
  for (int off = 32; off > 0; off >>= 1) s += __shfl_down(s, off);
  if (lane == 0) *sqp = s;
}

// Fused fp8 distance + group-min(9) + mean — BM=256, TRIPLE-BUFFER + counted
// vmcnt (T4). R9's dbuf had 1 syncthreads/iter whose compiler-emitted
// vmcnt(0) drain stalls all waves on loads with only 1 compute phase of
// slack. Now: 3 buffers, stage(i+2) in flight, per-iter sync =
// lgkmcnt(0)+vmcnt(7)+s_barrier -> tile i's loads had TWO compute phases.
// Staging rebalanced to UNIFORM 7 loads/wave (chunks 6w..6w+5 + chunk 24 by
// all 4 waves redundantly - identical-value LDS writes, benign) so the
// vmcnt immediate is wave-uniform.
// Sync proof: wave's own ds_reads done (lgkmcnt 0) + own stage(cur) done
// (vmcnt 7, in-order completion m135) BEFORE s_barrier => after barrier,
// buf[cur] fully staged by ALL waves, and buf[cur+2] (overwritten next) has
// no pending readers. Last iter peeled with vmcnt(0).
// CRITICAL (unchanged): every loop touching acc[][] FULLY UNROLLED — any
// runtime index scratches accumulators (tripwire: WRITE_SIZE must stay ~0).
// Grid 1D 512: b = bid&7 -> batch b on XCD b (fp8 L2-hot from convert).
// LDS chunks 1 KB = 16 rows x 64 fp8, XOR swizzle (slot ^ (row>>1)&3) ->
// conflict-free b128 fragment reads (verified R2-R9).
// LDS 3*25600 = 76800 B (>= 37120 epilogue), x2 blocks/CU = 153.6K <= 160K.
__global__ __launch_bounds__(256, 2) void dist_kernel(
    const unsigned char* __restrict__ x1q, const unsigned char* __restrict__ x2q,
    const float* __restrict__ sq1, const float* __restrict__ sq2,
    float* __restrict__ out) {
  __shared__ __align__(16) char smem[NBUF * BUFB];

  const int tid = threadIdx.x;
  const int wave = tid >> 6, lane = tid & 63;
  const int bid = blockIdx.x;
  const int b = bid & 7;          // batch -> XCD
  const int bm = (bid >> 3) & 7;  // fastest: A streams, B-tile L2-hot
  const int bn = bid >> 6;

  const unsigned char* Ag = x1q + ((size_t)b * N1 + bm * BM) * KD;
  const unsigned char* Bg = x2q + ((size_t)b * N2 + bn * BN) * KD;

  // staging: lane -> (row lr, 16B slot sl), fetch the swizzled global group
  const int lr = lane >> 2, sl = lane & 3;
  const int goff = (sl ^ ((lr >> 1) & 3)) * 16;

  // fragments: lane (fr, quad) reads swizzled slot -> global 16B group `quad`
  const int quad = lane >> 4, fr = lane & 15;
  const int fslot = (fr * 4 + (quad ^ ((fr >> 1) & 3))) * 16;

  f32x4 acc[4][9];
#pragma unroll
  for (int i = 0; i < 4; ++i)
#pragma unroll
    for (int j = 0; j < 9; ++j) {
      f32x4 z = {0.f, 0.f, 0.f, 0.f};
      acc[i][j] = z;
    }

  // stage(k0) into buffer `buf`: 25 chunks (0..15 = A 256 rows, 16..24 = B
  // 144). UNIFORM 7 VMEM/wave: chunks 6w..6w+5 per wave + chunk 24 by all.
  auto stage = [&](int buf, int k0) {
    char* base = smem + buf * BUFB;
#pragma unroll
    for (int t = 0; t < 6; ++t) {
      int j = wave * 6 + t;
      const unsigned char* g;
      if (j < 16)
        g = Ag + (size_t)(j * 16 + lr) * KD + k0 + goff;
      else
        g = Bg + (size_t)((j - 16) * 16 + lr) * KD + k0 + goff;
      async_copy16(g, base + j * 1024 + lane * 16);
    }
    // chunk 24 = B rows 128..143, staged redundantly by all 4 waves
    async_copy16(Bg + (size_t)(128 + lr) * KD + k0 + goff,
                 base + 24 * 1024 + lane * 16);
  };

#define COMPUTE(cbp)                                                          \
  {                                                                           \
    const char* cb = (cbp);                                                   \
    i64x2 a[4];                                                               \
    _Pragma("unroll") for (int tm = 0; tm < 4; ++tm)                          \
        a[tm] = *(const i64x2*)(cb + (wave * 4 + tm) * 1024 + fslot);         \
    _Pragma("unroll") for (int tn = 0; tn < 9; ++tn) {                        \
      i64x2 bf = *(const i64x2*)(cb + 16384 + tn * 1024 + fslot);             \
      _Pragma("unroll") for (int tm = 0; tm < 4; ++tm) {                      \
        acc[tm][tn] = __builtin_amdgcn_mfma_f32_16x16x32_fp8_fp8(             \
            a[tm].x, bf.x, acc[tm][tn], 0, 0, 0);                             \
        acc[tm][tn] = __builtin_amdgcn_mfma_f32_16x16x32_fp8_fp8(             \
            a[tm].y, bf.y, acc[tm][tn], 0, 0, 0);                             \
      }                                                                       \
    }                                                                         \
  }

  stage(0, 0);   // tiles 0,1 in flight (14 VMEM/wave)
  stage(1, 64);

  int cur = 0;
  for (int i = 0; i < 15; ++i) {
    // own prior ds_reads done + own stage(cur) done (in-order vmcnt), THEN
    // barrier => cross-wave: buf[cur] staged, overwrite target reader-free
    asm volatile("s_waitcnt lgkmcnt(0)" ::: "memory");
    asm volatile("s_waitcnt vmcnt(7)" ::: "memory");
    __builtin_amdgcn_s_barrier();
    __builtin_amdgcn_sched_barrier(0);
    if (i < 14) {
      int b2 = cur + 2;
      if (b2 >= NBUF) b2 -= NBUF;
      stage(b2, (i + 2) * 64);
    }
    COMPUTE(smem + cur * BUFB);
    ++cur;
    if (cur == NBUF) cur = 0;
  }
  // peeled last iter (tile 15, buffer 0): full drain allowed once
  asm volatile("s_waitcnt lgkmcnt(0)" ::: "memory");
  asm volatile("s_waitcnt vmcnt(0)" ::: "memory");
  __builtin_amdgcn_s_barrier();
  __builtin_amdgcn_sched_barrier(0);
  COMPUTE(smem + cur * BUFB);

  // ---- epilogue: d = sq1 + sq2 - 2*cross, min over 9-col groups, sum ----
  float s2[9];
#pragma unroll
  for (int tn = 0; tn < 9; ++tn)
    s2[tn] = sq2[(size_t)b * N2 + bn * BN + tn * 16 + fr];

  float s1v[4][4];
#pragma unroll
  for (int tm = 0; tm < 4; ++tm)
#pragma unroll
    for (int rr = 0; rr < 4; ++rr)
      s1v[tm][rr] = sq1[(size_t)b * N1 + bm * BM + wave * 64 + tm * 16 + quad * 4 + rr];

  float* eps = (float*)smem;
  float local = 0.f;
#pragma unroll  // FULL unroll: acc indices must be compile-time constants
  for (int tm = 0; tm < 4; ++tm) {
    __syncthreads();  // K-loop LDS / previous chunk fully consumed
    // D layout (16x16x32, dtype-independent): col = lane&15 (x2 row),
    // row = quad*4 + reg (x1 row). Chunk row = wave*16 + quad*4 + r.
#pragma unroll
    for (int tn = 0; tn < 9; ++tn)
#pragma unroll
      for (int rr = 0; rr < 4; ++rr)
        eps[(wave * 16 + quad * 4 + rr) * BNP + tn * 16 + fr] =
            s1v[tm][rr] + s2[tn] - 2.0f * acc[tm][tn][rr];
    __syncthreads();
    // 64 rows x 16 groups = 1024 groups, 4 per thread
#pragma unroll
    for (int qq = 0; qq < 4; ++qq) {
      int g = tid + qq * 256;
      int row = g >> 4, grp = g & 15;
      const float* p = eps + row * BNP + grp * 9;
      float mn = p[0];
#pragma unroll
      for (int jj = 1; jj < 9; ++jj) mn = fminf(mn, p[jj]);
      local += mn;
    }
  }

#pragma unroll
  for (int off = 32; off > 0; off >>= 1) local += __shfl_down(local, off);
  __syncthreads();
  if (lane == 0) eps[wave] = local;
  __syncthreads();
  if (tid == 0) {
    float s = eps[0] + eps[1] + eps[2] + eps[3];
    // total group count = 8 * 2048 * 1152 / 9 = 2097152
    atomicAdd(out, s * (1.0f / 2097152.0f));
  }
}

extern "C" void kernel_launch(void* const* d_in, const int* in_sizes, int n_in,
                              void* d_out, int out_size, void* d_ws, size_t ws_size,
                              hipStream_t stream) {
  const float* x1 = (const float*)d_in[0];
  const float* x2 = (const float*)d_in[1];
  char* ws = (char*)d_ws;
  const size_t x1q_bytes = (size_t)NB * N1 * KD;  // 16777216
  const size_t x2q_bytes = (size_t)NB * N2 * KD;  // 9437184
  unsigned char* x1q = (unsigned char*)ws;
  unsigned char* x2q = (unsigned char*)(ws + x1q_bytes);
  float* sq1 = (float*)(ws + x1q_bytes + x2q_bytes);
  float* sq2 = (float*)(ws + x1q_bytes + x2q_bytes + (size_t)NB * N1 * 4);

  convert_kernel<<<NB * (N1 / 4 + N2 / 4), 256, 0, stream>>>(x1, x2, x1q, x2q,
                                                             sq1, sq2,
                                                             (float*)d_out);
  dist_kernel<<<NB * (N1 / BM) * (N2 / BN), 256, 0, stream>>>(x1q, x2q, sq1, sq2,
                                                              (float*)d_out);
}